// Round 3
// baseline (1229.777 us; speedup 1.0000x reference)
//
#include <hip/hip_runtime.h>
#include <hip/hip_bf16.h>

// TreeLSTM on MI355X. ALL float tensors are fp32 on the wire (reference dtypes).
// Structure hard-coded from reference _build_forest():
//   128 trees, heap layout, TREE_SIZE=511, depth 9, node_order = 8 - depth.
//   Level lvl processes nodes at depth d = 8 - lvl. Children of heap h: 2h+1, 2h+2.
// Layers (N_LAYER=2) independent; processed sequentially reusing h/c buffers.
// h/c state stored as bf16 in ws (footprint 33.5 MB; rounding error ~0.01 << 0.057 thr).

#define IN_F 128
#define HF   128
#define TS   511
#define NT   128
#define NN   (NT * TS)   // 65408
#define NBL  32          // leaves per block
#define NBI  16          // internal nodes per block

typedef __hip_bfloat16 bf16;

__device__ __forceinline__ float b2f(bf16 x) { return __bfloat162float(x); }
__device__ __forceinline__ float sig_(float x) { return 1.0f / (1.0f + __expf(-x)); }
__device__ __forceinline__ float tanh_(float x) {
    float a = fabsf(x);
    float t = __expf(-2.0f * a);
    float r = (1.0f - t) / (1.0f + t);
    return copysignf(r, x);
}

// wp[((l*128 + k)*128 + t)*8 + j], j = {Wi_i, Wi_o, Wi_u, Wf, Ui_i, Ui_o, Ui_u, Uf}[t][k]
// bp[(l*128 + t)*4 + j] = {b_i, b_o, b_u, b_f}[t]
__global__ void pack_kernel(const float* __restrict__ Wiou, const float* __restrict__ biou,
                            const float* __restrict__ Uiou, const float* __restrict__ Wf,
                            const float* __restrict__ bfv, const float* __restrict__ Uf,
                            float* __restrict__ wp, float* __restrict__ bp) {
    int tid = blockIdx.x * blockDim.x + threadIdx.x;   // 0..32767
    int t = tid & 127;
    int k = (tid >> 7) & 127;
    int l = tid >> 14;
    float* dst = wp + (size_t)(((l * 128) + k) * 128 + t) * 8;
    dst[0] = Wiou[(l * 384 + t) * 128 + k];
    dst[1] = Wiou[(l * 384 + 128 + t) * 128 + k];
    dst[2] = Wiou[(l * 384 + 256 + t) * 128 + k];
    dst[3] = Wf[(l * 128 + t) * 128 + k];
    dst[4] = Uiou[(l * 384 + t) * 128 + k];
    dst[5] = Uiou[(l * 384 + 128 + t) * 128 + k];
    dst[6] = Uiou[(l * 384 + 256 + t) * 128 + k];
    dst[7] = Uf[(l * 128 + t) * 128 + k];
    if (k == 0) {
        float* bd = bp + (l * 128 + t) * 4;
        bd[0] = biou[l * 384 + t];
        bd[1] = biou[l * 384 + 128 + t];
        bd[2] = biou[l * 384 + 256 + t];
        bd[3] = bfv[l * 128 + t];
    }
}

// Leaves (level 0, depth 8): iou = b + Wi*x only. NBL leaves per 128-thread block.
__global__ __launch_bounds__(128) void leaf_kernel(
        const float* __restrict__ feat, const float* __restrict__ wp,
        const float* __restrict__ bp, bf16* __restrict__ h, bf16* __restrict__ c, int l) {
    __shared__ float xs[NBL][IN_F];
    const int t = threadIdx.x;
    const int j0 = blockIdx.x * NBL;
#pragma unroll
    for (int m = 0; m < NBL; m++) {
        int j = j0 + m;
        int node = (j >> 8) * TS + 255 + (j & 255);
        xs[m][t] = feat[(size_t)node * IN_F + t];
    }
    __syncthreads();

    const float* bd = bp + (l * 128 + t) * 4;
    float bi = bd[0], bo = bd[1], bu = bd[2];
    float ai[NBL], ao[NBL], au[NBL];
#pragma unroll
    for (int m = 0; m < NBL; m++) { ai[m] = bi; ao[m] = bo; au[m] = bu; }

    const float* wbase = wp + (size_t)((l * 128) * 128 + t) * 8;
    for (int k = 0; k < 128; k += 4) {
        // dst[0..3] = {Wi_i, Wi_o, Wi_u, Wf}; only .x/.y/.z used here
        float4 wa = *(const float4*)(wbase + (size_t)(k + 0) * 1024);
        float4 wb = *(const float4*)(wbase + (size_t)(k + 1) * 1024);
        float4 wc = *(const float4*)(wbase + (size_t)(k + 2) * 1024);
        float4 wd = *(const float4*)(wbase + (size_t)(k + 3) * 1024);
#pragma unroll
        for (int m = 0; m < NBL; m++) {
            float4 xv = *(const float4*)&xs[m][k];
            ai[m] += wa.x * xv.x + wb.x * xv.y + wc.x * xv.z + wd.x * xv.w;
            ao[m] += wa.y * xv.x + wb.y * xv.y + wc.y * xv.z + wd.y * xv.w;
            au[m] += wa.z * xv.x + wb.z * xv.y + wc.z * xv.z + wd.z * xv.w;
        }
    }
#pragma unroll
    for (int m = 0; m < NBL; m++) {
        int j = j0 + m;
        int node = (j >> 8) * TS + 255 + (j & 255);
        float i = sig_(ai[m]), o = sig_(ao[m]), u = tanh_(au[m]);
        float cn = i * u;
        float hn = o * tanh_(cn);
        h[(size_t)node * HF + t] = __float2bfloat16(hn);
        c[(size_t)node * HF + t] = __float2bfloat16(cn);
    }
}

// Internal levels: depth d in [0,7]. NBI nodes per 128-thread block.
__global__ __launch_bounds__(128) void level_kernel(
        const float* __restrict__ feat, const float* __restrict__ wp,
        const float* __restrict__ bp, bf16* __restrict__ h, bf16* __restrict__ c,
        int l, int d) {
    __shared__ float xs[NBI][128], hss[NBI][128], h0s[NBI][128], h1s[NBI][128];
    const int t = threadIdx.x;
    const int j0 = blockIdx.x * NBI;
#pragma unroll
    for (int m = 0; m < NBI; m++) {
        int j = j0 + m;
        int tree = j >> d;
        int heap = (1 << d) - 1 + (j & ((1 << d) - 1));
        int node = tree * TS + heap;
        int ch0 = tree * TS + 2 * heap + 1;
        xs[m][t] = feat[(size_t)node * IN_F + t];
        float a = b2f(h[(size_t)ch0 * HF + t]);
        float b = b2f(h[(size_t)(ch0 + 1) * HF + t]);
        h0s[m][t] = a; h1s[m][t] = b; hss[m][t] = a + b;
    }
    __syncthreads();

    const float* bd = bp + (l * 128 + t) * 4;
    float bi = bd[0], bo = bd[1], bu = bd[2], bfv = bd[3];
    float ai[NBI], ao[NBI], au[NBI], awf[NBI], af0[NBI], af1[NBI];
#pragma unroll
    for (int m = 0; m < NBI; m++) {
        ai[m] = bi; ao[m] = bo; au[m] = bu; awf[m] = bfv; af0[m] = 0.f; af1[m] = 0.f;
    }

    const float* wbase = wp + (size_t)((l * 128) * 128 + t) * 8;
    for (int k = 0; k < 128; k++) {
        // w0 = {Wi_i, Wi_o, Wi_u, Wf},  w1 = {Ui_i, Ui_o, Ui_u, Uf}
        float4 w0 = *(const float4*)(wbase + (size_t)k * 1024);
        float4 w1 = *(const float4*)(wbase + (size_t)k * 1024 + 4);
#pragma unroll
        for (int m = 0; m < NBI; m++) {
            float xv  = xs[m][k];
            float hv  = hss[m][k];
            float h0v = h0s[m][k];
            float h1v = h1s[m][k];
            ai[m]  += w0.x * xv + w1.x * hv;
            ao[m]  += w0.y * xv + w1.y * hv;
            au[m]  += w0.z * xv + w1.z * hv;
            awf[m] += w0.w * xv;
            af0[m] += w1.w * h0v;
            af1[m] += w1.w * h1v;
        }
    }
#pragma unroll
    for (int m = 0; m < NBI; m++) {
        int j = j0 + m;
        int tree = j >> d;
        int heap = (1 << d) - 1 + (j & ((1 << d) - 1));
        int node = tree * TS + heap;
        int ch0 = tree * TS + 2 * heap + 1;
        float i = sig_(ai[m]), o = sig_(ao[m]), u = tanh_(au[m]);
        float f0 = sig_(awf[m] + af0[m]);
        float f1 = sig_(awf[m] + af1[m]);
        float cc0 = b2f(c[(size_t)ch0 * HF + t]);
        float cc1 = b2f(c[(size_t)(ch0 + 1) * HF + t]);
        float cn = i * u + f0 * cc0 + f1 * cc1;
        float hn = o * tanh_(cn);
        h[(size_t)node * HF + t] = __float2bfloat16(hn);
        c[(size_t)node * HF + t] = __float2bfloat16(cn);
    }
}

// Roots are heap index 0 => node = tree*TS. Output: f_h (2,128,128) then f_c (2,128,128), fp32.
__global__ void gather_kernel(const bf16* __restrict__ h, const bf16* __restrict__ c,
                              float* __restrict__ out, int l) {
    int tid = blockIdx.x * blockDim.x + threadIdx.x;  // 0..16383
    int r = tid >> 7, t = tid & 127;
    size_t node = (size_t)r * TS;
    out[(size_t)(l * 128 + r) * 128 + t] = b2f(h[node * HF + t]);
    out[(size_t)2 * 128 * 128 + (size_t)(l * 128 + r) * 128 + t] = b2f(c[node * HF + t]);
}

extern "C" void kernel_launch(void* const* d_in, const int* in_sizes, int n_in,
                              void* d_out, int out_size, void* d_ws, size_t ws_size,
                              hipStream_t stream) {
    const float* feat = (const float*)d_in[0];
    const float* Wiou = (const float*)d_in[1];
    const float* biou = (const float*)d_in[2];
    const float* Uiou = (const float*)d_in[3];
    const float* Wf   = (const float*)d_in[4];
    const float* bfv  = (const float*)d_in[5];
    const float* Uf   = (const float*)d_in[6];
    float* out = (float*)d_out;

    // ws layout: h bf16[NN*128] | c bf16[NN*128] | wp f32[2*128*128*8] | bp f32[1024]
    // total ~34.6 MB
    bf16* h = (bf16*)d_ws;
    bf16* c = h + (size_t)NN * HF;
    float* wp = (float*)(c + (size_t)NN * HF);
    float* bp = wp + (size_t)2 * 128 * 128 * 8;

    pack_kernel<<<128, 256, 0, stream>>>(Wiou, biou, Uiou, Wf, bfv, Uf, wp, bp);

    for (int l = 0; l < 2; l++) {
        leaf_kernel<<<(NT * 256) / NBL, 128, 0, stream>>>(feat, wp, bp, h, c, l);
        for (int lvl = 1; lvl < 9; lvl++) {
            int d = 8 - lvl;                 // depth of nodes at this level
            int npl = NT << d;               // nodes at this level
            level_kernel<<<npl / NBI, 128, 0, stream>>>(feat, wp, bp, h, c, l, d);
        }
        gather_kernel<<<(NT * 128) / 256, 256, 0, stream>>>(h, c, out, l);
    }
}

// Round 4
// 767.142 us; speedup vs baseline: 1.6031x; 1.6031x over previous
//
#include <hip/hip_runtime.h>
#include <hip/hip_bf16.h>

// TreeLSTM on MI355X — MFMA formulation.
// Structure hard-coded: 128 trees, heap layout, TREE_SIZE=511, depth 9.
// Level at depth d: nodes [2^d-1, 2^(d+1)-1) per tree; children 2h+1, 2h+2.
// Per internal node: gates = [x | h0+h1 | h0 | h1] (K=512) @ B (512x640),
//   B col blocks [i|o|u|f0|f1]: x->Wi (iou cols) & Wf (f0,f1 cols);
//   hsum->Ui (iou); h0->Uf (f0); h1->Uf (f1); zeros elsewhere.
// Leaves: A=[x] K=128, cols [i|o|u] (384).
// d=8 (leaves) + d=7..4 via MFMA GEMM; d=3..0 + root gather fused per-tree VALU.
// Layers sequential (shared h/c buffers, ws ~35.9 MB).

#define TS 511
#define NT 128
#define NN (NT * TS)   // 65408

typedef __hip_bfloat16 bf16;
typedef __attribute__((ext_vector_type(8))) short short8;
typedef __attribute__((ext_vector_type(4))) short short4v;
typedef __attribute__((ext_vector_type(4))) float floatx4;

__device__ __forceinline__ unsigned short f2b(float f) {
    return __builtin_bit_cast(unsigned short, __float2bfloat16(f));
}
__device__ __forceinline__ float b2f_u(unsigned short u) {
    unsigned v = (unsigned)u << 16;
    return __builtin_bit_cast(float, v);
}
__device__ __forceinline__ float sig_(float x) { return 1.0f / (1.0f + __expf(-x)); }
__device__ __forceinline__ float tanh_(float x) {
    float a = fabsf(x);
    float t = __expf(-2.0f * a);
    float r = (1.0f - t) / (1.0f + t);
    return copysignf(r, x);
}

// ---------------- weight packing ----------------
// Bg[((l*16 + kb)*640 + n)*32 + k']  bf16, k = kb*32+k', n = g*128+o
// bp5[(l*5 + g)*128 + o] fp32 biases (g=3,4 both b_f)
__global__ void pack_b(const float* __restrict__ Wiou, const float* __restrict__ biou,
                       const float* __restrict__ Uiou, const float* __restrict__ Wf,
                       const float* __restrict__ bfv, const float* __restrict__ Uf,
                       unsigned short* __restrict__ Bg, float* __restrict__ bp5) {
    int tid = blockIdx.x * 256 + threadIdx.x;   // 0..655359
    if (tid < 1280) {
        int l = tid / 640, r = tid % 640, g = r >> 7, o = r & 127;
        bp5[tid] = (g < 3) ? biou[l * 384 + r] : bfv[l * 128 + o];
    }
    int l = tid / 327680;
    int r2 = tid % 327680;
    int n = r2 >> 9, k = r2 & 511;
    int g = n >> 7, o = n & 127;
    float v = 0.f;
    if (g < 3) {
        if (k < 128)       v = Wiou[(l * 384 + g * 128 + o) * 128 + k];
        else if (k < 256)  v = Uiou[(l * 384 + g * 128 + o) * 128 + (k - 128)];
    } else if (g == 3) {
        if (k < 128)                  v = Wf[(l * 128 + o) * 128 + k];
        else if (k >= 256 && k < 384) v = Uf[(l * 128 + o) * 128 + (k - 256)];
    } else {
        if (k < 128)       v = Wf[(l * 128 + o) * 128 + k];
        else if (k >= 384) v = Uf[(l * 128 + o) * 128 + (k - 384)];
    }
    Bg[((size_t)(l * 16 + (k >> 5)) * 640 + n) * 32 + (k & 31)] = f2b(v);
}

// wp[((l*128 + k)*128 + t)*8 + j], j = {Wi_i,Wi_o,Wi_u,Wf, Ui_i,Ui_o,Ui_u,Uf}[t][k]
// bp[(l*128 + t)*4] = {b_i,b_o,b_u,b_f}  (for the VALU tail)
__global__ void pack_w(const float* __restrict__ Wiou, const float* __restrict__ biou,
                       const float* __restrict__ Uiou, const float* __restrict__ Wf,
                       const float* __restrict__ bfv, const float* __restrict__ Uf,
                       float* __restrict__ wp, float* __restrict__ bp) {
    int tid = blockIdx.x * blockDim.x + threadIdx.x;   // 0..32767
    int t = tid & 127;
    int k = (tid >> 7) & 127;
    int l = tid >> 14;
    float* dst = wp + (size_t)(((l * 128) + k) * 128 + t) * 8;
    dst[0] = Wiou[(l * 384 + t) * 128 + k];
    dst[1] = Wiou[(l * 384 + 128 + t) * 128 + k];
    dst[2] = Wiou[(l * 384 + 256 + t) * 128 + k];
    dst[3] = Wf[(l * 128 + t) * 128 + k];
    dst[4] = Uiou[(l * 384 + t) * 128 + k];
    dst[5] = Uiou[(l * 384 + 128 + t) * 128 + k];
    dst[6] = Uiou[(l * 384 + 256 + t) * 128 + k];
    dst[7] = Uf[(l * 128 + t) * 128 + k];
    if (k == 0) {
        float* bd = bp + (l * 128 + t) * 4;
        bd[0] = biou[l * 384 + t];
        bd[1] = biou[l * 384 + 128 + t];
        bd[2] = biou[l * 384 + 256 + t];
        bd[3] = bfv[l * 128 + t];
    }
}

// ---------------- MFMA level GEMM ----------------
// Block: 64 nodes x NCOLS cols. 512 threads = 8 waves (2 M-groups x 4 N-groups).
// Wave tile 32M x (NCOLS/4)N; per K-step(32): 2 a_frags + NI b_frags, 2*NI mfma.
// LDS: As[64][40] bf16 | Bs[NCOLS][40] bf16 (union w/ epilogue Lg[32][656] bf16).
template <int NKB, int NCOLS, bool LEAF>
__global__ __launch_bounds__(512) void gemm_level(
        const float* __restrict__ feat, const unsigned short* __restrict__ Bg,
        const float* __restrict__ bp5, unsigned short* __restrict__ h,
        unsigned short* __restrict__ c, int l, int d) {
    constexpr int NI = NCOLS / 64;       // n-tiles per wave
    constexpr int BS_BYTES = NCOLS * 40 * 2;
    constexpr int LG_BYTES = 32 * 656 * 2;
    __shared__ char smem[5120 + (BS_BYTES > LG_BYTES ? BS_BYTES : LG_BYTES)];
    unsigned short* As = (unsigned short*)smem;
    unsigned short* Bs = (unsigned short*)(smem + 5120);
    unsigned short* Lg = (unsigned short*)(smem + 5120);

    const int tid = threadIdx.x;
    const int lane = tid & 63, wave = tid >> 6;
    const int wm = wave & 1, wn = wave >> 1;
    const int quad = lane >> 4, l15 = lane & 15;

    // A-staging indices: 8 threads per node, 4 k-elems each
    const int s = tid & 7, nl_st = tid >> 3;
    const int j_st = blockIdx.x * 64 + nl_st;
    int node_st, ch0_st = 0;
    if (LEAF) {
        node_st = (j_st >> 8) * TS + 255 + (j_st & 255);
    } else {
        int tree = j_st >> d, idx = j_st & ((1 << d) - 1);
        int heap = (1 << d) - 1 + idx;
        node_st = tree * TS + heap;
        ch0_st = tree * TS + 2 * heap + 1;
    }

    floatx4 acc[2][NI];
#pragma unroll
    for (int mi = 0; mi < 2; mi++)
#pragma unroll
        for (int ni = 0; ni < NI; ni++)
            acc[mi][ni] = (floatx4){0.f, 0.f, 0.f, 0.f};

    for (int kb = 0; kb < NKB; kb++) {
        __syncthreads();
        // stage B: contiguous slab Bg[l][kb][n][32] -> Bs[n][40]
        const unsigned short* Bsrc = Bg + ((size_t)(l * 16 + kb) * 640) * 32;
#pragma unroll
        for (int i = 0; i < NCOLS / 128; i++) {
            int flat = i * 512 + tid;
            int n = flat >> 2, chk = flat & 3;
            *(int4*)(Bs + n * 40 + chk * 8) = *(const int4*)(Bsrc + (size_t)n * 32 + chk * 8);
        }
        // stage A: [x | hsum | h0 | h1] row for this node
        if (LEAF || kb < 4) {
            float4 xv = *(const float4*)(feat + (size_t)node_st * 128 + kb * 32 + s * 4);
            short4v r;
            r[0] = (short)f2b(xv.x); r[1] = (short)f2b(xv.y);
            r[2] = (short)f2b(xv.z); r[3] = (short)f2b(xv.w);
            *(short4v*)(As + nl_st * 40 + s * 4) = r;
        } else if (kb < 8) {
            int k0 = (kb - 4) * 32 + s * 4;
            short4v a = *(const short4v*)(h + (size_t)ch0_st * 128 + k0);
            short4v b = *(const short4v*)(h + (size_t)(ch0_st + 1) * 128 + k0);
            short4v r;
#pragma unroll
            for (int e = 0; e < 4; e++)
                r[e] = (short)f2b(b2f_u((unsigned short)a[e]) + b2f_u((unsigned short)b[e]));
            *(short4v*)(As + nl_st * 40 + s * 4) = r;
        } else if (kb < 12) {
            int k0 = (kb - 8) * 32 + s * 4;
            *(short4v*)(As + nl_st * 40 + s * 4) =
                *(const short4v*)(h + (size_t)ch0_st * 128 + k0);
        } else {
            int k0 = (kb - 12) * 32 + s * 4;
            *(short4v*)(As + nl_st * 40 + s * 4) =
                *(const short4v*)(h + (size_t)(ch0_st + 1) * 128 + k0);
        }
        __syncthreads();
        // compute: A-frag lane = row l15, k=quad*8+j ; B-frag lane = col l15, k=quad*8+j
        short8 a0 = *(const short8*)(As + (wm * 32 + l15) * 40 + quad * 8);
        short8 a1 = *(const short8*)(As + (wm * 32 + 16 + l15) * 40 + quad * 8);
#pragma unroll
        for (int ni = 0; ni < NI; ni++) {
            short8 b = *(const short8*)(Bs + (wn * (NCOLS / 4) + ni * 16 + l15) * 40 + quad * 8);
            acc[0][ni] = __builtin_amdgcn_mfma_f32_16x16x32_bf16(a0, b, acc[0][ni], 0, 0, 0);
            acc[1][ni] = __builtin_amdgcn_mfma_f32_16x16x32_bf16(a1, b, acc[1][ni], 0, 0, 0);
        }
    }

    // epilogue: per M-half, dump gates to LDS (bf16) then elementwise
    const int nl_ep = tid >> 4;           // node within half
    const int t0 = (tid & 15) * 8;        // 8 feature cols per thread
    for (int half = 0; half < 2; half++) {
        __syncthreads();
        if (wm == half) {
#pragma unroll
            for (int mi = 0; mi < 2; mi++)
#pragma unroll
                for (int ni = 0; ni < NI; ni++)
#pragma unroll
                    for (int r = 0; r < 4; r++) {
                        int row = mi * 16 + quad * 4 + r;   // C/D: row=quad*4+reg
                        int col = wn * (NCOLS / 4) + ni * 16 + l15;
                        Lg[row * 656 + col] = f2b(acc[mi][ni][r]);
                    }
        }
        __syncthreads();
        int j = blockIdx.x * 64 + half * 32 + nl_ep;
        int node, ch0 = 0;
        if (LEAF) {
            node = (j >> 8) * TS + 255 + (j & 255);
        } else {
            int tree = j >> d, idx = j & ((1 << d) - 1);
            int heap = (1 << d) - 1 + idx;
            node = tree * TS + heap;
            ch0 = tree * TS + 2 * heap + 1;
        }
        const unsigned short* Lr = Lg + nl_ep * 656 + t0;
        short8 gI = *(const short8*)(Lr);
        short8 gO = *(const short8*)(Lr + 128);
        short8 gU = *(const short8*)(Lr + 256);
        const float* bb = bp5 + (size_t)l * 640 + t0;
        short8 hr, cr;
        if (LEAF) {
#pragma unroll
            for (int e = 0; e < 8; e++) {
                float iv = sig_(b2f_u((unsigned short)gI[e]) + bb[e]);
                float ov = sig_(b2f_u((unsigned short)gO[e]) + bb[128 + e]);
                float uv = tanh_(b2f_u((unsigned short)gU[e]) + bb[256 + e]);
                float cn = iv * uv;
                float hn = ov * tanh_(cn);
                hr[e] = (short)f2b(hn);
                cr[e] = (short)f2b(cn);
            }
        } else {
            short8 gF0 = *(const short8*)(Lr + 384);
            short8 gF1 = *(const short8*)(Lr + 512);
            short8 c0 = *(const short8*)(c + (size_t)ch0 * 128 + t0);
            short8 c1 = *(const short8*)(c + (size_t)(ch0 + 1) * 128 + t0);
#pragma unroll
            for (int e = 0; e < 8; e++) {
                float iv = sig_(b2f_u((unsigned short)gI[e]) + bb[e]);
                float ov = sig_(b2f_u((unsigned short)gO[e]) + bb[128 + e]);
                float uv = tanh_(b2f_u((unsigned short)gU[e]) + bb[256 + e]);
                float f0 = sig_(b2f_u((unsigned short)gF0[e]) + bb[384 + e]);
                float f1 = sig_(b2f_u((unsigned short)gF1[e]) + bb[512 + e]);
                float cn = iv * uv + f0 * b2f_u((unsigned short)c0[e])
                                   + f1 * b2f_u((unsigned short)c1[e]);
                float hn = ov * tanh_(cn);
                hr[e] = (short)f2b(hn);
                cr[e] = (short)f2b(cn);
            }
        }
        *(short8*)(h + (size_t)node * 128 + t0) = hr;
        *(short8*)(c + (size_t)node * 128 + t0) = cr;
    }
}

// ---------------- fused tail: d=3..0 + root gather (VALU, 1 block per tree) --------
__global__ __launch_bounds__(128) void tail_kernel(
        const float* __restrict__ feat, const float* __restrict__ wp,
        const float* __restrict__ bp, unsigned short* __restrict__ h,
        unsigned short* __restrict__ c, float* __restrict__ out, int l) {
    __shared__ float xs[8][128], hss[8][128], h0s[8][128], h1s[8][128];
    const int t = threadIdx.x, tree = blockIdx.x;
    const float* bd = bp + (l * 128 + t) * 4;
    const float bi = bd[0], bo = bd[1], bu = bd[2], bfv = bd[3];
    const float* wbase = wp + ((size_t)(l * 128) * 128 + t) * 8;
    for (int dd = 3; dd >= 0; dd--) {
        const int nd = 1 << dd;
        __syncthreads();
        for (int m = 0; m < 8; m++) {     // m >= nd duplicates a node (benign)
            int heap = nd - 1 + (m & (nd - 1));
            int node = tree * TS + heap;
            int ch0 = tree * TS + 2 * heap + 1;
            xs[m][t] = feat[(size_t)node * 128 + t];
            float a = b2f_u(h[(size_t)ch0 * 128 + t]);
            float b = b2f_u(h[(size_t)(ch0 + 1) * 128 + t]);
            h0s[m][t] = a; h1s[m][t] = b; hss[m][t] = a + b;
        }
        __syncthreads();
        float ai[8], ao[8], au[8], awf[8], af0[8], af1[8];
#pragma unroll
        for (int m = 0; m < 8; m++) {
            ai[m] = bi; ao[m] = bo; au[m] = bu; awf[m] = bfv; af0[m] = 0.f; af1[m] = 0.f;
        }
        for (int k = 0; k < 128; k++) {
            float4 w0 = *(const float4*)(wbase + (size_t)k * 1024);
            float4 w1 = *(const float4*)(wbase + (size_t)k * 1024 + 4);
#pragma unroll
            for (int m = 0; m < 8; m++) {
                float xv = xs[m][k], hv = hss[m][k], h0v = h0s[m][k], h1v = h1s[m][k];
                ai[m]  += w0.x * xv + w1.x * hv;
                ao[m]  += w0.y * xv + w1.y * hv;
                au[m]  += w0.z * xv + w1.z * hv;
                awf[m] += w0.w * xv;
                af0[m] += w1.w * h0v;
                af1[m] += w1.w * h1v;
            }
        }
#pragma unroll
        for (int m = 0; m < 8; m++) {
            int heap = nd - 1 + (m & (nd - 1));
            int node = tree * TS + heap;
            int ch0 = tree * TS + 2 * heap + 1;
            float iv = sig_(ai[m]), ov = sig_(ao[m]), uv = tanh_(au[m]);
            float f0 = sig_(awf[m] + af0[m]);
            float f1 = sig_(awf[m] + af1[m]);
            float cc0 = b2f_u(c[(size_t)ch0 * 128 + t]);
            float cc1 = b2f_u(c[(size_t)(ch0 + 1) * 128 + t]);
            float cn = iv * uv + f0 * cc0 + f1 * cc1;
            float hn = ov * tanh_(cn);
            h[(size_t)node * 128 + t] = f2b(hn);
            c[(size_t)node * 128 + t] = f2b(cn);
            if (dd == 0 && m == 0) {
                out[(size_t)(l * 128 + tree) * 128 + t] = hn;
                out[32768 + (size_t)(l * 128 + tree) * 128 + t] = cn;
            }
        }
    }
}

extern "C" void kernel_launch(void* const* d_in, const int* in_sizes, int n_in,
                              void* d_out, int out_size, void* d_ws, size_t ws_size,
                              hipStream_t stream) {
    const float* feat = (const float*)d_in[0];
    const float* Wiou = (const float*)d_in[1];
    const float* biou = (const float*)d_in[2];
    const float* Uiou = (const float*)d_in[3];
    const float* Wf   = (const float*)d_in[4];
    const float* bfv  = (const float*)d_in[5];
    const float* Uf   = (const float*)d_in[6];
    float* out = (float*)d_out;

    // ws: h bf16[NN*128] | c bf16[NN*128] | Bg bf16[2*16*640*32] | wp f32[2*128*128*8]
    //     | bp f32[1024] | bp5 f32[1280]   total ~35.9 MB
    unsigned short* h = (unsigned short*)d_ws;
    unsigned short* c = h + (size_t)NN * 128;
    unsigned short* Bg = c + (size_t)NN * 128;
    float* wp = (float*)(Bg + (size_t)2 * 16 * 640 * 32);
    float* bp = wp + (size_t)2 * 128 * 128 * 8;
    float* bp5 = bp + 1024;

    pack_b<<<2560, 256, 0, stream>>>(Wiou, biou, Uiou, Wf, bfv, Uf, Bg, bp5);
    pack_w<<<128, 256, 0, stream>>>(Wiou, biou, Uiou, Wf, bfv, Uf, wp, bp);

    for (int l = 0; l < 2; l++) {
        // leaves: 32768 nodes, 512 blocks
        gemm_level<4, 384, true><<<512, 512, 0, stream>>>(feat, Bg, bp5, h, c, l, 0);
        // internal big levels d=7..4
        for (int d = 7; d >= 4; d--)
            gemm_level<16, 640, false><<<(2 << d), 512, 0, stream>>>(feat, Bg, bp5, h, c, l, d);
        // d=3..0 + root output
        tail_kernel<<<128, 128, 0, stream>>>(feat, wp, bp, h, c, out, l);
    }
}

// Round 5
// 445.792 us; speedup vs baseline: 2.7586x; 1.7209x over previous
//
#include <hip/hip_runtime.h>
#include <hip/hip_bf16.h>

// TreeLSTM on MI355X — MFMA formulation, round 5.
// Structure hard-coded: 128 trees, heap layout, TREE_SIZE=511, depth 9.
// Level at depth d: nodes [2^d-1, 2^(d+1)-1) per tree; children 2h+1, 2h+2.
// Gates GEMM: A-row = [x | h0+h1 | h0 | h1] (K=512) @ B (512x640), col blocks
//   [i|o|u|f0|f1] with zero blocks enforcing gate structure.
// d=8 (leaves, K=128) + d=7..5 via gemm_level; d=4..0 + root out via tail_mfma
//   (per-tree block, h/c of tail levels cached in LDS, B-frags straight from L2).
// Layers sequential (shared h/c buffers). ws ~36.2 MB.

#define TS 511
#define NT 128
#define NN (NT * TS)   // 65408

typedef __hip_bfloat16 bf16;
typedef __attribute__((ext_vector_type(8))) short short8;
typedef __attribute__((ext_vector_type(4))) short short4v;
typedef __attribute__((ext_vector_type(4))) float floatx4;

__device__ __forceinline__ unsigned short f2b(float f) {
    return __builtin_bit_cast(unsigned short, __float2bfloat16(f));
}
__device__ __forceinline__ float b2f_u(unsigned short u) {
    unsigned v = (unsigned)u << 16;
    return __builtin_bit_cast(float, v);
}
__device__ __forceinline__ float sig_(float x) { return 1.0f / (1.0f + __expf(-x)); }
__device__ __forceinline__ float tanh_(float x) {
    float a = fabsf(x);
    float t = __expf(-2.0f * a);
    float r = (1.0f - t) / (1.0f + t);
    return copysignf(r, x);
}

// ---------------- weight packing ----------------
// Bg[((l*16 + kb)*640 + n)*32 + k']  bf16, k = kb*32+k', n = g*128+o
// bp5[(l*5 + g)*128 + o] fp32 biases (g=3,4 both b_f)
__global__ void pack_b(const float* __restrict__ Wiou, const float* __restrict__ biou,
                       const float* __restrict__ Uiou, const float* __restrict__ Wf,
                       const float* __restrict__ bfv, const float* __restrict__ Uf,
                       unsigned short* __restrict__ Bg, float* __restrict__ bp5) {
    int tid = blockIdx.x * 256 + threadIdx.x;   // 0..655359
    if (tid < 1280) {
        int l = tid / 640, r = tid % 640, g = r >> 7, o = r & 127;
        bp5[tid] = (g < 3) ? biou[l * 384 + r] : bfv[l * 128 + o];
    }
    int l = tid / 327680;
    int r2 = tid % 327680;
    int n = r2 >> 9, k = r2 & 511;
    int g = n >> 7, o = n & 127;
    float v = 0.f;
    if (g < 3) {
        if (k < 128)       v = Wiou[(l * 384 + g * 128 + o) * 128 + k];
        else if (k < 256)  v = Uiou[(l * 384 + g * 128 + o) * 128 + (k - 128)];
    } else if (g == 3) {
        if (k < 128)                  v = Wf[(l * 128 + o) * 128 + k];
        else if (k >= 256 && k < 384) v = Uf[(l * 128 + o) * 128 + (k - 256)];
    } else {
        if (k < 128)       v = Wf[(l * 128 + o) * 128 + k];
        else if (k >= 384) v = Uf[(l * 128 + o) * 128 + (k - 384)];
    }
    Bg[((size_t)(l * 16 + (k >> 5)) * 640 + n) * 32 + (k & 31)] = f2b(v);
}

// ---------------- MFMA level GEMM (big levels) ----------------
// Block: 64 nodes x NCOLS cols. 512 threads = 8 waves (2 M-groups x 4 N-groups).
template <int NKB, int NCOLS, bool LEAF>
__global__ __launch_bounds__(512) void gemm_level(
        const float* __restrict__ feat, const unsigned short* __restrict__ Bg,
        const float* __restrict__ bp5, unsigned short* __restrict__ h,
        unsigned short* __restrict__ c, int l, int d) {
    constexpr int NI = NCOLS / 64;       // n-tiles per wave
    constexpr int BS_BYTES = NCOLS * 40 * 2;
    constexpr int LG_BYTES = 32 * 656 * 2;
    __shared__ char smem[5120 + (BS_BYTES > LG_BYTES ? BS_BYTES : LG_BYTES)];
    unsigned short* As = (unsigned short*)smem;
    unsigned short* Bs = (unsigned short*)(smem + 5120);
    unsigned short* Lg = (unsigned short*)(smem + 5120);

    const int tid = threadIdx.x;
    const int lane = tid & 63, wave = tid >> 6;
    const int wm = wave & 1, wn = wave >> 1;
    const int quad = lane >> 4, l15 = lane & 15;

    const int s = tid & 7, nl_st = tid >> 3;
    const int j_st = blockIdx.x * 64 + nl_st;
    int node_st, ch0_st = 0;
    if (LEAF) {
        node_st = (j_st >> 8) * TS + 255 + (j_st & 255);
    } else {
        int tree = j_st >> d, idx = j_st & ((1 << d) - 1);
        int heap = (1 << d) - 1 + idx;
        node_st = tree * TS + heap;
        ch0_st = tree * TS + 2 * heap + 1;
    }

    floatx4 acc[2][NI];
#pragma unroll
    for (int mi = 0; mi < 2; mi++)
#pragma unroll
        for (int ni = 0; ni < NI; ni++)
            acc[mi][ni] = (floatx4){0.f, 0.f, 0.f, 0.f};

    for (int kb = 0; kb < NKB; kb++) {
        __syncthreads();
        const unsigned short* Bsrc = Bg + ((size_t)(l * 16 + kb) * 640) * 32;
#pragma unroll
        for (int i = 0; i < NCOLS / 128; i++) {
            int flat = i * 512 + tid;
            int n = flat >> 2, chk = flat & 3;
            *(int4*)(Bs + n * 40 + chk * 8) = *(const int4*)(Bsrc + (size_t)n * 32 + chk * 8);
        }
        if (LEAF || kb < 4) {
            float4 xv = *(const float4*)(feat + (size_t)node_st * 128 + kb * 32 + s * 4);
            short4v r;
            r[0] = (short)f2b(xv.x); r[1] = (short)f2b(xv.y);
            r[2] = (short)f2b(xv.z); r[3] = (short)f2b(xv.w);
            *(short4v*)(As + nl_st * 40 + s * 4) = r;
        } else if (kb < 8) {
            int k0 = (kb - 4) * 32 + s * 4;
            short4v a = *(const short4v*)(h + (size_t)ch0_st * 128 + k0);
            short4v b = *(const short4v*)(h + (size_t)(ch0_st + 1) * 128 + k0);
            short4v r;
#pragma unroll
            for (int e = 0; e < 4; e++)
                r[e] = (short)f2b(b2f_u((unsigned short)a[e]) + b2f_u((unsigned short)b[e]));
            *(short4v*)(As + nl_st * 40 + s * 4) = r;
        } else if (kb < 12) {
            int k0 = (kb - 8) * 32 + s * 4;
            *(short4v*)(As + nl_st * 40 + s * 4) =
                *(const short4v*)(h + (size_t)ch0_st * 128 + k0);
        } else {
            int k0 = (kb - 12) * 32 + s * 4;
            *(short4v*)(As + nl_st * 40 + s * 4) =
                *(const short4v*)(h + (size_t)(ch0_st + 1) * 128 + k0);
        }
        __syncthreads();
        short8 a0 = *(const short8*)(As + (wm * 32 + l15) * 40 + quad * 8);
        short8 a1 = *(const short8*)(As + (wm * 32 + 16 + l15) * 40 + quad * 8);
#pragma unroll
        for (int ni = 0; ni < NI; ni++) {
            short8 b = *(const short8*)(Bs + (wn * (NCOLS / 4) + ni * 16 + l15) * 40 + quad * 8);
            acc[0][ni] = __builtin_amdgcn_mfma_f32_16x16x32_bf16(a0, b, acc[0][ni], 0, 0, 0);
            acc[1][ni] = __builtin_amdgcn_mfma_f32_16x16x32_bf16(a1, b, acc[1][ni], 0, 0, 0);
        }
    }

    const int nl_ep = tid >> 4;
    const int t0 = (tid & 15) * 8;
    for (int half = 0; half < 2; half++) {
        __syncthreads();
        if (wm == half) {
#pragma unroll
            for (int mi = 0; mi < 2; mi++)
#pragma unroll
                for (int ni = 0; ni < NI; ni++)
#pragma unroll
                    for (int r = 0; r < 4; r++) {
                        int row = mi * 16 + quad * 4 + r;
                        int col = wn * (NCOLS / 4) + ni * 16 + l15;
                        Lg[row * 656 + col] = f2b(acc[mi][ni][r]);
                    }
        }
        __syncthreads();
        int j = blockIdx.x * 64 + half * 32 + nl_ep;
        int node, ch0 = 0;
        if (LEAF) {
            node = (j >> 8) * TS + 255 + (j & 255);
        } else {
            int tree = j >> d, idx = j & ((1 << d) - 1);
            int heap = (1 << d) - 1 + idx;
            node = tree * TS + heap;
            ch0 = tree * TS + 2 * heap + 1;
        }
        const unsigned short* Lr = Lg + nl_ep * 656 + t0;
        short8 gI = *(const short8*)(Lr);
        short8 gO = *(const short8*)(Lr + 128);
        short8 gU = *(const short8*)(Lr + 256);
        const float* bb = bp5 + (size_t)l * 640 + t0;
        short8 hr, cr;
        if (LEAF) {
#pragma unroll
            for (int e = 0; e < 8; e++) {
                float iv = sig_(b2f_u((unsigned short)gI[e]) + bb[e]);
                float ov = sig_(b2f_u((unsigned short)gO[e]) + bb[128 + e]);
                float uv = tanh_(b2f_u((unsigned short)gU[e]) + bb[256 + e]);
                float cn = iv * uv;
                float hn = ov * tanh_(cn);
                hr[e] = (short)f2b(hn);
                cr[e] = (short)f2b(cn);
            }
        } else {
            short8 gF0 = *(const short8*)(Lr + 384);
            short8 gF1 = *(const short8*)(Lr + 512);
            short8 c0 = *(const short8*)(c + (size_t)ch0 * 128 + t0);
            short8 c1 = *(const short8*)(c + (size_t)(ch0 + 1) * 128 + t0);
#pragma unroll
            for (int e = 0; e < 8; e++) {
                float iv = sig_(b2f_u((unsigned short)gI[e]) + bb[e]);
                float ov = sig_(b2f_u((unsigned short)gO[e]) + bb[128 + e]);
                float uv = tanh_(b2f_u((unsigned short)gU[e]) + bb[256 + e]);
                float f0 = sig_(b2f_u((unsigned short)gF0[e]) + bb[384 + e]);
                float f1 = sig_(b2f_u((unsigned short)gF1[e]) + bb[512 + e]);
                float cn = iv * uv + f0 * b2f_u((unsigned short)c0[e])
                                   + f1 * b2f_u((unsigned short)c1[e]);
                float hn = ov * tanh_(cn);
                hr[e] = (short)f2b(hn);
                cr[e] = (short)f2b(cn);
            }
        }
        *(short8*)(h + (size_t)node * 128 + t0) = hr;
        *(short8*)(c + (size_t)node * 128 + t0) = cr;
    }
}

// ---------------- MFMA tail: d=4..0 + root out, one block per tree ----------------
// 512 threads = 8 waves, each wave 80 cols (5 n-tiles). M=16 covers nd<=16.
// B-fragments read directly from global Bg (L2-resident, coalesced dwordx4).
// Tail-level h/c live in LDS cache (heaps 0..30), never written to HBM.
__global__ __launch_bounds__(512) void tail_mfma(
        const float* __restrict__ feat, const unsigned short* __restrict__ Bg,
        const float* __restrict__ bp5, const unsigned short* __restrict__ h,
        const unsigned short* __restrict__ c, float* __restrict__ out, int l) {
    // smem: [As 16*16*40 | Lg 16*656] union (21248 B) + hcH[31][136] + hcC[31][136]
    __shared__ char smem[21248 + 2 * 31 * 136 * 2];
    unsigned short* As  = (unsigned short*)smem;              // [kb][row][40]
    unsigned short* Lg  = (unsigned short*)smem;              // [row][656]
    unsigned short* hcH = (unsigned short*)(smem + 21248);    // [heap][136]
    unsigned short* hcC = hcH + 31 * 136;

    const int tid = threadIdx.x;
    const int tree = blockIdx.x;
    const int lane = tid & 63, wave = tid >> 6;
    const int quad = lane >> 4, l15 = lane & 15;
    const unsigned short* Bb = Bg + (size_t)(l * 16) * 640 * 32;

    for (int dd = 4; dd >= 0; dd--) {
        const int nd = 1 << dd;
        __syncthreads();   // prev-level hc writes & Lg->As overwrite
        // ---- stage A: 256 (row,kb) pairs, 2 threads (halves) each, 16 elems/thread
        {
            int pair = tid >> 1, half = tid & 1;
            int row = pair >> 4, kb = pair & 15;
            unsigned short* dst = As + (kb * 16 + row) * 40 + half * 16;
            if (row < nd) {
                int heap = nd - 1 + row;
                int k0 = (kb & 3) * 32 + half * 16;
                float v[16];
                if (kb < 4) {
                    const float* src = feat + ((size_t)tree * TS + heap) * 128 + k0;
#pragma unroll
                    for (int e = 0; e < 16; e++) v[e] = src[e];
                } else if (dd == 4) {
                    const unsigned short* g0 =
                        h + ((size_t)tree * TS + 2 * heap + 1) * 128 + k0;
                    const unsigned short* g1 = g0 + 128;
                    if (kb < 8) {
#pragma unroll
                        for (int e = 0; e < 16; e++) v[e] = b2f_u(g0[e]) + b2f_u(g1[e]);
                    } else if (kb < 12) {
#pragma unroll
                        for (int e = 0; e < 16; e++) v[e] = b2f_u(g0[e]);
                    } else {
#pragma unroll
                        for (int e = 0; e < 16; e++) v[e] = b2f_u(g1[e]);
                    }
                } else {
                    const unsigned short* s0 = hcH + (2 * heap + 1) * 136 + k0;
                    const unsigned short* s1 = s0 + 136;
                    if (kb < 8) {
#pragma unroll
                        for (int e = 0; e < 16; e++) v[e] = b2f_u(s0[e]) + b2f_u(s1[e]);
                    } else if (kb < 12) {
#pragma unroll
                        for (int e = 0; e < 16; e++) v[e] = b2f_u(s0[e]);
                    } else {
#pragma unroll
                        for (int e = 0; e < 16; e++) v[e] = b2f_u(s1[e]);
                    }
                }
                short8 r0, r1;
#pragma unroll
                for (int e = 0; e < 8; e++) {
                    r0[e] = (short)f2b(v[e]);
                    r1[e] = (short)f2b(v[e + 8]);
                }
                *(short8*)dst = r0;
                *(short8*)(dst + 8) = r1;
            } else {
                short8 z = (short8){0, 0, 0, 0, 0, 0, 0, 0};
                *(short8*)dst = z;
                *(short8*)(dst + 8) = z;
            }
        }
        __syncthreads();
        // ---- K-loop: 16 steps, b-frags straight from global ----
        floatx4 acc[5];
#pragma unroll
        for (int ni = 0; ni < 5; ni++) acc[ni] = (floatx4){0.f, 0.f, 0.f, 0.f};
        for (int kb = 0; kb < 16; kb++) {
            short8 a = *(const short8*)(As + (kb * 16 + l15) * 40 + quad * 8);
#pragma unroll
            for (int ni = 0; ni < 5; ni++) {
                int col = wave * 80 + ni * 16 + l15;
                short8 b = *(const short8*)(Bb + ((size_t)kb * 640 + col) * 32 + quad * 8);
                acc[ni] = __builtin_amdgcn_mfma_f32_16x16x32_bf16(a, b, acc[ni], 0, 0, 0);
            }
        }
        __syncthreads();   // As reads done before Lg overwrite (alias)
        // ---- dump gates ----
#pragma unroll
        for (int ni = 0; ni < 5; ni++)
#pragma unroll
            for (int r = 0; r < 4; r++) {
                int row = quad * 4 + r;
                int col = wave * 80 + ni * 16 + l15;
                Lg[row * 656 + col] = f2b(acc[ni][r]);
            }
        __syncthreads();
        // ---- elementwise update into LDS hc cache ----
        for (int idx = tid; idx < nd * 128; idx += 512) {
            int node = idx >> 7, t = idx & 127;
            int heap = nd - 1 + node;
            const unsigned short* Lr = Lg + node * 656;
            const float* bb = bp5 + (size_t)l * 640;
            float iv = sig_(b2f_u(Lr[t]) + bb[t]);
            float ov = sig_(b2f_u(Lr[128 + t]) + bb[128 + t]);
            float uv = tanh_(b2f_u(Lr[256 + t]) + bb[256 + t]);
            float f0 = sig_(b2f_u(Lr[384 + t]) + bb[384 + t]);
            float f1 = sig_(b2f_u(Lr[512 + t]) + bb[512 + t]);
            float c0v, c1v;
            if (dd == 4) {
                const unsigned short* cc = c + ((size_t)tree * TS + 2 * heap + 1) * 128;
                c0v = b2f_u(cc[t]);
                c1v = b2f_u(cc[128 + t]);
            } else {
                c0v = b2f_u(hcC[(2 * heap + 1) * 136 + t]);
                c1v = b2f_u(hcC[(2 * heap + 2) * 136 + t]);
            }
            float cn = iv * uv + f0 * c0v + f1 * c1v;
            float hn = ov * tanh_(cn);
            hcH[heap * 136 + t] = f2b(hn);
            hcC[heap * 136 + t] = f2b(cn);
            if (dd == 0) {
                out[(size_t)(l * 128 + tree) * 128 + t] = hn;
                out[32768 + (size_t)(l * 128 + tree) * 128 + t] = cn;
            }
        }
    }
}

extern "C" void kernel_launch(void* const* d_in, const int* in_sizes, int n_in,
                              void* d_out, int out_size, void* d_ws, size_t ws_size,
                              hipStream_t stream) {
    const float* feat = (const float*)d_in[0];
    const float* Wiou = (const float*)d_in[1];
    const float* biou = (const float*)d_in[2];
    const float* Uiou = (const float*)d_in[3];
    const float* Wf   = (const float*)d_in[4];
    const float* bfv  = (const float*)d_in[5];
    const float* Uf   = (const float*)d_in[6];
    float* out = (float*)d_out;

    // ws: h bf16[NN*128] | c bf16[NN*128] | Bg bf16[2*16*640*32] | bp5 f32[1280]
    // total ~36.2 MB
    unsigned short* h = (unsigned short*)d_ws;
    unsigned short* c = h + (size_t)NN * 128;
    unsigned short* Bg = c + (size_t)NN * 128;
    float* bp5 = (float*)(Bg + (size_t)2 * 16 * 640 * 32);

    pack_b<<<2560, 256, 0, stream>>>(Wiou, biou, Uiou, Wf, bfv, Uf, Bg, bp5);

    for (int l = 0; l < 2; l++) {
        // leaves: 32768 nodes, 512 blocks
        gemm_level<4, 384, true><<<512, 512, 0, stream>>>(feat, Bg, bp5, h, c, l, 0);
        // internal big levels d=7..5
        for (int d = 7; d >= 5; d--)
            gemm_level<16, 640, false><<<(2 << d), 512, 0, stream>>>(feat, Bg, bp5, h, c, l, d);
        // d=4..0 + root output
        tail_mfma<<<128, 512, 0, stream>>>(feat, Bg, bp5, h, c, out, l);
    }
}